// Round 8
// baseline (366.664 us; speedup 1.0000x reference)
//
#include <hip/hip_runtime.h>
#include <math.h>

#define NN 50000
#define NE 800000
#define ED 128
#define FD 512
#define QKV_BLOCKS (NN / 16)                // 3125
#define HIST_BLOCKS ((NE / 4 + 255) / 256)  // 782
#define SCAN_BLOCKS ((NN + 255) / 256)      // 196

typedef __attribute__((ext_vector_type(8))) short bf16x8;
typedef __attribute__((ext_vector_type(4))) float f32x4;

static __device__ __forceinline__ float wave_sum(float x) {
#pragma unroll
  for (int off = 32; off > 0; off >>= 1) x += __shfl_xor(x, off, 64);
  return x;
}

static __device__ __forceinline__ int wave_sum_i(int x) {
#pragma unroll
  for (int off = 32; off > 0; off >>= 1) x += __shfl_xor(x, off, 64);
  return x;
}

static __device__ __forceinline__ unsigned short f2bf(float f) {
  union { float f; unsigned u; } c; c.f = f;
  unsigned r = c.u + 0x7fffu + ((c.u >> 16) & 1u);
  return (unsigned short)(r >> 16);
}

static __device__ __forceinline__ float2 bfpair(unsigned u) {
  union { unsigned a; float f; } lo, hi;
  lo.a = u << 16; hi.a = u & 0xffff0000u;
  return make_float2(lo.f, hi.f);
}

// ---- one-time weight swizzle to fragment-major bf16 + deg zero ----
__global__ void k_prep(const float* __restrict__ Wqkv, const float* __restrict__ W1,
                       const float* __restrict__ W2, unsigned short* __restrict__ WqkvF,
                       unsigned short* __restrict__ W1F, unsigned short* __restrict__ W2F,
                       int* __restrict__ deg) {
  int idx = blockIdx.x * 256 + threadIdx.x;  // 65536 threads
  if (idx < NN) deg[idx] = 0;
  if (idx < 49152) {  // WqkvF: t<24, kb<4
    int j = idx & 7, l = (idx >> 3) & 63, kb = (idx >> 9) & 3, t = idx >> 11;
    int k = kb * 32 + (l >> 4) * 8 + j, n = t * 16 + (l & 15);
    WqkvF[idx] = f2bf(Wqkv[k * 384 + n]);
  }
  {  // W1F: t<32, kb<4
    int j = idx & 7, l = (idx >> 3) & 63, kb = (idx >> 9) & 3, t = idx >> 11;
    int k = kb * 32 + (l >> 4) * 8 + j, n = t * 16 + (l & 15);
    W1F[idx] = f2bf(W1[k * 512 + n]);
  }
  {  // W2F: t<8, kb<16
    int j = idx & 7, l = (idx >> 3) & 63, kb = (idx >> 9) & 15, t = idx >> 13;
    int k = kb * 32 + (l >> 4) * 8 + j, n = t * 16 + (l & 15);
    W2F[idx] = f2bf(W2[k * 128 + n]);
  }
}

// ---- fused: QKV GEMM blocks + histogram blocks ----
__global__ __launch_bounds__(256) void k_qkv_hist(
    const float* __restrict__ X, const unsigned short* __restrict__ WqkvF,
    const float* __restrict__ B, unsigned short* __restrict__ q,
    unsigned short* __restrict__ k, unsigned short* __restrict__ v,
    const int* __restrict__ src, int* __restrict__ deg) {
  __shared__ unsigned short xs[16][136];
  const int tid = threadIdx.x;
  if (blockIdx.x >= QKV_BLOCKS) {
    const int e0 = ((blockIdx.x - QKV_BLOCKS) * 256 + tid) * 4;
    if (e0 < NE) {
      int4 s4 = *(const int4*)&src[e0];
      atomicAdd(&deg[s4.x], 1);
      atomicAdd(&deg[s4.y], 1);
      atomicAdd(&deg[s4.z], 1);
      atomicAdd(&deg[s4.w], 1);
    }
    return;
  }
  const int row0 = blockIdx.x * 16;
  for (int idx = tid; idx < 512; idx += 256) {
    int r = idx >> 5, c4 = (idx & 31) << 2;
    float4 val = *(const float4*)&X[(size_t)(row0 + r) * ED + c4];
    xs[r][c4] = f2bf(val.x); xs[r][c4 + 1] = f2bf(val.y);
    xs[r][c4 + 2] = f2bf(val.z); xs[r][c4 + 3] = f2bf(val.w);
  }
  __syncthreads();
  const int wv = tid >> 6, lane = tid & 63;
  const int ln = lane & 15, quad = lane >> 4;
  const int koff = quad * 8;
  bf16x8 a[4];
#pragma unroll
  for (int kb = 0; kb < 4; kb++) a[kb] = *(const bf16x8*)&xs[ln][kb * 32 + koff];
  for (int g = 0; g < 3; g++) {
    const int t0 = wv * 6 + g * 2;
    bf16x8 b[2][4];
#pragma unroll
    for (int j = 0; j < 2; j++)
#pragma unroll
      for (int kb = 0; kb < 4; kb++)
        b[j][kb] = *(const bf16x8*)&WqkvF[(size_t)(((t0 + j) * 4 + kb) * 64 + lane) * 8];
    f32x4 acc[2];
#pragma unroll
    for (int j = 0; j < 2; j++) acc[j] = (f32x4){0.f, 0.f, 0.f, 0.f};
#pragma unroll
    for (int kb = 0; kb < 4; kb++)
#pragma unroll
      for (int j = 0; j < 2; j++)
        acc[j] = __builtin_amdgcn_mfma_f32_16x16x32_bf16(a[kb], b[j][kb], acc[j], 0, 0, 0);
#pragma unroll
    for (int j = 0; j < 2; j++) {
      const int col = (t0 + j) * 16 + ln;
      const float bias = B[col];
      unsigned short* dst = (col < 128) ? q : (col < 256) ? k : v;
      const int c = col & 127;
#pragma unroll
      for (int r = 0; r < 4; r++)
        dst[(size_t)(row0 + quad * 4 + r) * ED + c] = f2bf(acc[j][r] + bias);
    }
  }
}

// ---- three-phase parallel scan ----
__global__ __launch_bounds__(256) void k_scan1(const int* __restrict__ deg,
                                               int* __restrict__ blocksum) {
  const int tid = threadIdx.x;
  const int i = blockIdx.x * 256 + tid;
  int d = (i < NN) ? deg[i] : 0;
  int w = wave_sum_i(d);
  __shared__ int ws[4];
  if ((tid & 63) == 0) ws[tid >> 6] = w;
  __syncthreads();
  if (tid == 0) blocksum[blockIdx.x] = ws[0] + ws[1] + ws[2] + ws[3];
}

__global__ __launch_bounds__(256) void k_scan2(int* __restrict__ blocksum,
                                               int* __restrict__ blockpre) {
  __shared__ int s[256];
  const int t = threadIdx.x;
  int d = (t < SCAN_BLOCKS) ? blocksum[t] : 0;
  s[t] = d;
  __syncthreads();
  for (int off = 1; off < 256; off <<= 1) {
    int add = (t >= off) ? s[t - off] : 0;
    __syncthreads();
    s[t] += add;
    __syncthreads();
  }
  if (t < SCAN_BLOCKS) blockpre[t] = s[t] - d;  // exclusive
}

__global__ __launch_bounds__(256) void k_scan3(const int* __restrict__ deg,
                                               const int* __restrict__ blockpre,
                                               int* __restrict__ row_start,
                                               int* __restrict__ cursor) {
  __shared__ int s[256];
  const int t = threadIdx.x;
  const int i = blockIdx.x * 256 + t;
  int d = (i < NN) ? deg[i] : 0;
  s[t] = d;
  __syncthreads();
  for (int off = 1; off < 256; off <<= 1) {
    int add = (t >= off) ? s[t - off] : 0;
    __syncthreads();
    s[t] += add;
    __syncthreads();
  }
  const int pre = blockpre[blockIdx.x] + s[t] - d;
  if (i < NN) {
    row_start[i] = pre;
    cursor[i] = pre;
  }
  if (i == NN) row_start[NN] = pre;
}

__global__ void k_scatter(const int* __restrict__ src, const int* __restrict__ dst,
                          int* __restrict__ cursor, int* __restrict__ colidx) {
  const int e0 = (blockIdx.x * 256 + threadIdx.x) * 4;
  if (e0 < NE) {
    int4 s4 = *(const int4*)&src[e0];
    int4 d4 = *(const int4*)&dst[e0];
    colidx[atomicAdd(&cursor[s4.x], 1)] = d4.x;
    colidx[atomicAdd(&cursor[s4.y], 1)] = d4.y;
    colidx[atomicAdd(&cursor[s4.z], 1)] = d4.z;
    colidx[atomicAdd(&cursor[s4.w], 1)] = d4.w;
  }
}

// ---- attention chunk: softmax without max tracking (logits ~N(0,1)) ----
template <bool FULL>
static __device__ __forceinline__ void attn_chunk(
    int base, int cnt, int lane, int grp, int gl, const float* qf,
    const unsigned short* __restrict__ k, const unsigned short* __restrict__ v,
    const int* __restrict__ colidx, int* sc, float* se,
    float& l, float& ax, float& ay) {
  const int C = FULL ? 16 : cnt;
  if (lane < C) sc[lane] = colidx[base + lane];
#pragma unroll
  for (int it = 0; it < 4; it++) {
    const int t = it * 4 + grp;
    float dot = 0.f;
    if (FULL || t < C) {
      const int c = sc[t];
      uint4 kw = *(const uint4*)&k[(size_t)c * ED + gl * 8];
      float2 p0 = bfpair(kw.x), p1 = bfpair(kw.y), p2 = bfpair(kw.z), p3 = bfpair(kw.w);
      dot = qf[0] * p0.x + qf[1] * p0.y + qf[2] * p1.x + qf[3] * p1.y +
            qf[4] * p2.x + qf[5] * p2.y + qf[6] * p3.x + qf[7] * p3.y;
    }
    dot += __shfl_xor(dot, 1, 64);
    dot += __shfl_xor(dot, 2, 64);
    dot += __shfl_xor(dot, 4, 64);
    dot += __shfl_xor(dot, 8, 64);
    if (gl == 0 && (FULL || t < C))
      se[t] = __expf(dot * 0.08838834764831845f);  // 128^-0.5
  }
#pragma unroll
  for (int t = 0; t < 16; t++) {
    if (FULL || t < C) {
      const int c = sc[t];
      const float e = se[t];
      float2 v2 = bfpair(*(const unsigned*)&v[(size_t)c * ED + 2 * lane]);
      l += e;
      ax = fmaf(e, v2.x, ax);
      ay = fmaf(e, v2.y, ay);
    }
  }
}

// ---- FUSED: attention + LN1 + FFN + LN2 ; 16 nodes/block, 4 waves ----
__global__ __launch_bounds__(256) void k_attn_ffn(
    const unsigned short* __restrict__ q, const unsigned short* __restrict__ k,
    const unsigned short* __restrict__ v, const float* __restrict__ x,
    const int* __restrict__ row_start, const int* __restrict__ colidx,
    const float* __restrict__ g1, const float* __restrict__ be1,
    const unsigned short* __restrict__ W1F, const float* __restrict__ b1,
    const unsigned short* __restrict__ W2F, const float* __restrict__ b2,
    const float* __restrict__ g2, const float* __restrict__ be2,
    float* __restrict__ out) {
  __shared__ unsigned short xs[16][136];  // x1 tile (bf16) for FFN GEMM1
  __shared__ unsigned short hs[16][520];  // h tile; later aliased ys f32[16][132]
  __shared__ int scol[4][16];
  __shared__ float sexp[4][16];
  float* ys = (float*)&hs[0][0];
  const int tid = threadIdx.x;
  const int wv = tid >> 6, lane = tid & 63;
  const int grp = lane >> 4, gl = lane & 15;
  const int row0 = blockIdx.x * 16;  // NN % 16 == 0
  int* sc = scol[wv]; float* se = sexp[wv];
  const float2 gg1 = *(const float2*)&g1[2 * lane];
  const float2 bb1 = *(const float2*)&be1[2 * lane];

  float x1f[4][2];  // fp32 x1 rows (this wave's 4 nodes) for LN2 residual

  // ---- phase 1: attention + LN1 for 4 nodes (rows wv*4 .. wv*4+3) ----
#pragma unroll
  for (int i = 0; i < 4; i++) {
    const int node = row0 + wv * 4 + i;
    float qf[8];
    {
      uint4 qw = *(const uint4*)&q[(size_t)node * ED + gl * 8];
      float2 p0 = bfpair(qw.x), p1 = bfpair(qw.y), p2 = bfpair(qw.z), p3 = bfpair(qw.w);
      qf[0] = p0.x; qf[1] = p0.y; qf[2] = p1.x; qf[3] = p1.y;
      qf[4] = p2.x; qf[5] = p2.y; qf[6] = p3.x; qf[7] = p3.y;
    }
    const int r0 = row_start[node], r1 = row_start[node + 1];
    float l = 0.f, ax = 0.f, ay = 0.f;
    int base = r0;
    for (; base + 16 <= r1; base += 16)
      attn_chunk<true>(base, 16, lane, grp, gl, qf, k, v, colidx, sc, se, l, ax, ay);
    if (base < r1)
      attn_chunk<false>(base, r1 - base, lane, grp, gl, qf, k, v, colidx, sc, se, l, ax, ay);

    const float inv = (r1 > r0) ? 1.0f / l : 0.f;
    float2 xv = *(const float2*)&x[(size_t)node * ED + 2 * lane];
    float vx = xv.x + ax * inv;
    float vy = xv.y + ay * inv;
    float mean = wave_sum(vx + vy) * (1.f / ED);
    float dx = vx - mean, dy = vy - mean;
    float var = wave_sum(dx * dx + dy * dy) * (1.f / ED);
    float rstd = rsqrtf(var + 1e-5f);
    float ox = dx * rstd * gg1.x + bb1.x;
    float oy = dy * rstd * gg1.y + bb1.y;
    x1f[i][0] = ox; x1f[i][1] = oy;
    unsigned pack = (unsigned)f2bf(ox) | ((unsigned)f2bf(oy) << 16);
    *(unsigned*)&xs[wv * 4 + i][2 * lane] = pack;
  }
  __syncthreads();

  // ---- phase 2: FFN GEMM1 h = relu(x1 @ W1 + b1) ----
  const int ln = lane & 15, quad = lane >> 4;
  const int koff = quad * 8;
  bf16x8 a1[4];
#pragma unroll
  for (int kb = 0; kb < 4; kb++) a1[kb] = *(const bf16x8*)&xs[ln][kb * 32 + koff];
  for (int g = 0; g < 4; g++) {
    const int t0 = wv * 8 + g * 2;
    bf16x8 b[2][4];
#pragma unroll
    for (int j = 0; j < 2; j++)
#pragma unroll
      for (int kb = 0; kb < 4; kb++)
        b[j][kb] = *(const bf16x8*)&W1F[(size_t)(((t0 + j) * 4 + kb) * 64 + lane) * 8];
    f32x4 acc[2];
#pragma unroll
    for (int j = 0; j < 2; j++) acc[j] = (f32x4){0.f, 0.f, 0.f, 0.f};
#pragma unroll
    for (int kb = 0; kb < 4; kb++)
#pragma unroll
      for (int j = 0; j < 2; j++)
        acc[j] = __builtin_amdgcn_mfma_f32_16x16x32_bf16(a1[kb], b[j][kb], acc[j], 0, 0, 0);
#pragma unroll
    for (int j = 0; j < 2; j++) {
      const int col = (t0 + j) * 16 + ln;
      const float bias = b1[col];
#pragma unroll
      for (int r = 0; r < 4; r++)
        hs[quad * 4 + r][col] = f2bf(fmaxf(acc[j][r] + bias, 0.f));
    }
  }
  __syncthreads();

  // ---- phase 3: FFN GEMM2 y = h @ W2 + b2 ----
  f32x4 acc2[2];
  acc2[0] = (f32x4){0.f, 0.f, 0.f, 0.f};
  acc2[1] = (f32x4){0.f, 0.f, 0.f, 0.f};
  const int nt0 = wv * 2;
  for (int kg = 0; kg < 4; kg++) {
    bf16x8 a[4];
#pragma unroll
    for (int kk = 0; kk < 4; kk++)
      a[kk] = *(const bf16x8*)&hs[ln][(kg * 4 + kk) * 32 + koff];
    bf16x8 b[2][4];
#pragma unroll
    for (int nt = 0; nt < 2; nt++)
#pragma unroll
      for (int kk = 0; kk < 4; kk++)
        b[nt][kk] = *(const bf16x8*)&W2F[(size_t)(((nt0 + nt) * 16 + kg * 4 + kk) * 64 + lane) * 8];
#pragma unroll
    for (int kk = 0; kk < 4; kk++)
#pragma unroll
      for (int nt = 0; nt < 2; nt++)
        acc2[nt] = __builtin_amdgcn_mfma_f32_16x16x32_bf16(a[kk], b[nt][kk], acc2[nt], 0, 0, 0);
  }
  __syncthreads();  // all hs reads done -> safe to alias as ys
#pragma unroll
  for (int nt = 0; nt < 2; nt++) {
    const int col = (nt0 + nt) * 16 + ln;
    const float bias = b2[col];
#pragma unroll
    for (int r = 0; r < 4; r++)
      ys[(quad * 4 + r) * 132 + col] = acc2[nt][r] + bias;
  }
  __syncthreads();

  // ---- phase 4: residual (x1 from regs) + LN2 -> out ----
  const float2 gg2 = *(const float2*)&g2[2 * lane];
  const float2 bb2 = *(const float2*)&be2[2 * lane];
#pragma unroll
  for (int rr = 0; rr < 4; rr++) {
    const int r = wv * 4 + rr;  // same rows this wave computed in phase 1
    float vx = ys[r * 132 + 2 * lane] + x1f[rr][0];
    float vy = ys[r * 132 + 2 * lane + 1] + x1f[rr][1];
    float mean = wave_sum(vx + vy) * (1.f / ED);
    float dx = vx - mean, dy = vy - mean;
    float var = wave_sum(dx * dx + dy * dy) * (1.f / ED);
    float rstd = rsqrtf(var + 1e-5f);
    float2 o = make_float2(dx * rstd * gg2.x + bb2.x, dy * rstd * gg2.y + bb2.y);
    *(float2*)&out[(size_t)(row0 + r) * ED + 2 * lane] = o;
  }
}

extern "C" void kernel_launch(void* const* d_in, const int* in_sizes, int n_in,
                              void* d_out, int out_size, void* d_ws, size_t ws_size,
                              hipStream_t stream) {
  const float* x = (const float*)d_in[0];
  const int* ei = (const int*)d_in[1];
  const float* W_qkv = (const float*)d_in[2];
  const float* b_qkv = (const float*)d_in[3];
  const float* W1 = (const float*)d_in[4];
  const float* b1 = (const float*)d_in[5];
  const float* W2 = (const float*)d_in[6];
  const float* b2 = (const float*)d_in[7];
  const float* g1 = (const float*)d_in[8];
  const float* be1 = (const float*)d_in[9];
  const float* g2 = (const float*)d_in[10];
  const float* be2 = (const float*)d_in[11];
  float* out = (float*)d_out;

  char* ws = (char*)d_ws;
  size_t off = 0;
  auto alloc = [&](size_t bytes) -> char* {
    char* p = ws + off;
    off = (off + bytes + 255) & ~(size_t)255;
    return p;
  };
  unsigned short* q = (unsigned short*)alloc(2 * (size_t)NN * ED);
  unsigned short* k = (unsigned short*)alloc(2 * (size_t)NN * ED);
  unsigned short* v = (unsigned short*)alloc(2 * (size_t)NN * ED);
  unsigned short* WqkvF = (unsigned short*)alloc(2 * 24 * 4 * 64 * 8);
  unsigned short* W1F = (unsigned short*)alloc(2 * 32 * 4 * 64 * 8);
  unsigned short* W2F = (unsigned short*)alloc(2 * 8 * 16 * 64 * 8);
  int* deg = (int*)alloc(sizeof(int) * NN);
  int* cursor = (int*)alloc(sizeof(int) * NN);
  int* row_start = (int*)alloc(sizeof(int) * (NN + 1));
  int* colidx = (int*)alloc(sizeof(int) * NE);
  int* blocksum = (int*)alloc(sizeof(int) * SCAN_BLOCKS);
  int* blockpre = (int*)alloc(sizeof(int) * SCAN_BLOCKS);

  k_prep<<<256, 256, 0, stream>>>(W_qkv, W1, W2, WqkvF, W1F, W2F, deg);
  k_qkv_hist<<<QKV_BLOCKS + HIST_BLOCKS, 256, 0, stream>>>(x, WqkvF, b_qkv, q, k, v, ei, deg);
  k_scan1<<<SCAN_BLOCKS, 256, 0, stream>>>(deg, blocksum);
  k_scan2<<<1, 256, 0, stream>>>(blocksum, blockpre);
  k_scan3<<<SCAN_BLOCKS, 256, 0, stream>>>(deg, blockpre, row_start, cursor);
  k_scatter<<<HIST_BLOCKS, 256, 0, stream>>>(ei, ei + NE, cursor, colidx);
  k_attn_ffn<<<NN / 16, 256, 0, stream>>>(q, k, v, x, row_start, colidx, g1, be1,
                                          W1F, b1, W2F, b2, g2, be2, out);
}

// Round 11
// 293.473 us; speedup vs baseline: 1.2494x; 1.2494x over previous
//
#include <hip/hip_runtime.h>
#include <math.h>

#define NN 50000
#define NE 800000
#define ED 128
#define FD 512
#define QKV_BLOCKS (NN / 16)                // 3125
#define HIST_BLOCKS ((NE / 4 + 255) / 256)  // 782
#define SCAN_BLOCKS ((NN + 255) / 256)      // 196

typedef __attribute__((ext_vector_type(8))) short bf16x8;
typedef __attribute__((ext_vector_type(4))) float f32x4;

static __device__ __forceinline__ float wave_sum(float x) {
#pragma unroll
  for (int off = 32; off > 0; off >>= 1) x += __shfl_xor(x, off, 64);
  return x;
}

static __device__ __forceinline__ int wave_sum_i(int x) {
#pragma unroll
  for (int off = 32; off > 0; off >>= 1) x += __shfl_xor(x, off, 64);
  return x;
}

static __device__ __forceinline__ unsigned short f2bf(float f) {
  union { float f; unsigned u; } c; c.f = f;
  unsigned r = c.u + 0x7fffu + ((c.u >> 16) & 1u);
  return (unsigned short)(r >> 16);
}

static __device__ __forceinline__ float2 bfpair(unsigned u) {
  union { unsigned a; float f; } lo, hi;
  lo.a = u << 16; hi.a = u & 0xffff0000u;
  return make_float2(lo.f, hi.f);
}

// ---- one-time weight swizzle to fragment-major bf16 + deg zero ----
__global__ void k_prep(const float* __restrict__ Wqkv, const float* __restrict__ W1,
                       const float* __restrict__ W2, unsigned short* __restrict__ WqkvF,
                       unsigned short* __restrict__ W1F, unsigned short* __restrict__ W2F,
                       int* __restrict__ deg) {
  int idx = blockIdx.x * 256 + threadIdx.x;  // 65536 threads
  if (idx < NN) deg[idx] = 0;
  if (idx < 49152) {  // WqkvF: t<24, kb<4
    int j = idx & 7, l = (idx >> 3) & 63, kb = (idx >> 9) & 3, t = idx >> 11;
    int k = kb * 32 + (l >> 4) * 8 + j, n = t * 16 + (l & 15);
    WqkvF[idx] = f2bf(Wqkv[k * 384 + n]);
  }
  {  // W1F: t<32, kb<4
    int j = idx & 7, l = (idx >> 3) & 63, kb = (idx >> 9) & 3, t = idx >> 11;
    int k = kb * 32 + (l >> 4) * 8 + j, n = t * 16 + (l & 15);
    W1F[idx] = f2bf(W1[k * 512 + n]);
  }
  {  // W2F: t<8, kb<16
    int j = idx & 7, l = (idx >> 3) & 63, kb = (idx >> 9) & 15, t = idx >> 13;
    int k = kb * 32 + (l >> 4) * 8 + j, n = t * 16 + (l & 15);
    W2F[idx] = f2bf(W2[k * 128 + n]);
  }
}

// ---- fused: QKV GEMM + histogram; q,k,v all bf16 ----
__global__ __launch_bounds__(256) void k_qkv_hist(
    const float* __restrict__ X, const unsigned short* __restrict__ WqkvF,
    const float* __restrict__ B, unsigned short* __restrict__ q,
    unsigned short* __restrict__ k, unsigned short* __restrict__ v,
    const int* __restrict__ src, int* __restrict__ deg) {
  __shared__ unsigned short xs[16][136];
  const int tid = threadIdx.x;
  if (blockIdx.x >= QKV_BLOCKS) {
    const int e0 = ((blockIdx.x - QKV_BLOCKS) * 256 + tid) * 4;
    if (e0 < NE) {
      int4 s4 = *(const int4*)&src[e0];
      atomicAdd(&deg[s4.x], 1);
      atomicAdd(&deg[s4.y], 1);
      atomicAdd(&deg[s4.z], 1);
      atomicAdd(&deg[s4.w], 1);
    }
    return;
  }
  const int row0 = blockIdx.x * 16;
  for (int idx = tid; idx < 512; idx += 256) {
    int r = idx >> 5, c4 = (idx & 31) << 2;
    float4 val = *(const float4*)&X[(size_t)(row0 + r) * ED + c4];
    xs[r][c4] = f2bf(val.x); xs[r][c4 + 1] = f2bf(val.y);
    xs[r][c4 + 2] = f2bf(val.z); xs[r][c4 + 3] = f2bf(val.w);
  }
  __syncthreads();
  const int wv = tid >> 6, lane = tid & 63;
  const int ln = lane & 15, quad = lane >> 4;
  const int koff = quad * 8;
  bf16x8 a[4];
#pragma unroll
  for (int kb = 0; kb < 4; kb++) a[kb] = *(const bf16x8*)&xs[ln][kb * 32 + koff];
  for (int g = 0; g < 3; g++) {
    const int t0 = wv * 6 + g * 2;
    bf16x8 b[2][4];
#pragma unroll
    for (int j = 0; j < 2; j++)
#pragma unroll
      for (int kb = 0; kb < 4; kb++)
        b[j][kb] = *(const bf16x8*)&WqkvF[(size_t)(((t0 + j) * 4 + kb) * 64 + lane) * 8];
    f32x4 acc[2];
#pragma unroll
    for (int j = 0; j < 2; j++) acc[j] = (f32x4){0.f, 0.f, 0.f, 0.f};
#pragma unroll
    for (int kb = 0; kb < 4; kb++)
#pragma unroll
      for (int j = 0; j < 2; j++)
        acc[j] = __builtin_amdgcn_mfma_f32_16x16x32_bf16(a[kb], b[j][kb], acc[j], 0, 0, 0);
#pragma unroll
    for (int j = 0; j < 2; j++) {
      const int col = (t0 + j) * 16 + ln;
      const float bias = B[col];
      unsigned short* dst = (col < 128) ? q : (col < 256) ? k : v;
      const int c = col & 127;
#pragma unroll
      for (int r = 0; r < 4; r++)
        dst[(size_t)(row0 + quad * 4 + r) * ED + c] = f2bf(acc[j][r] + bias);
    }
  }
}

// ---- two-phase parallel scan ----
__global__ __launch_bounds__(256) void k_scan1(const int* __restrict__ deg,
                                               int* __restrict__ blocksum) {
  const int tid = threadIdx.x;
  const int i = blockIdx.x * 256 + tid;
  int d = (i < NN) ? deg[i] : 0;
  int w = wave_sum_i(d);
  __shared__ int ws[4];
  if ((tid & 63) == 0) ws[tid >> 6] = w;
  __syncthreads();
  if (tid == 0) blocksum[blockIdx.x] = ws[0] + ws[1] + ws[2] + ws[3];
}

__global__ __launch_bounds__(256) void k_scan3(const int* __restrict__ deg,
                                               const int* __restrict__ blocksum,
                                               int* __restrict__ row_start,
                                               int* __restrict__ cursor) {
  __shared__ int bs[256];
  __shared__ int s[256];
  const int t = threadIdx.x;
  int bsv = (t < SCAN_BLOCKS) ? blocksum[t] : 0;
  bs[t] = bsv;
  __syncthreads();
  for (int off = 1; off < 256; off <<= 1) {
    int add = (t >= off) ? bs[t - off] : 0;
    __syncthreads();
    bs[t] += add;
    __syncthreads();
  }
  const int blockpre = (blockIdx.x > 0) ? bs[blockIdx.x - 1] : 0;
  const int i = blockIdx.x * 256 + t;
  int d = (i < NN) ? deg[i] : 0;
  s[t] = d;
  __syncthreads();
  for (int off = 1; off < 256; off <<= 1) {
    int add = (t >= off) ? s[t - off] : 0;
    __syncthreads();
    s[t] += add;
    __syncthreads();
  }
  const int pre = blockpre + s[t] - d;
  if (i < NN) {
    row_start[i] = pre;
    cursor[i] = pre;
  }
  if (i == NN) row_start[NN] = pre;
}

__global__ void k_scatter(const int* __restrict__ src, const int* __restrict__ dst,
                          int* __restrict__ cursor, int* __restrict__ colidx) {
  const int e0 = (blockIdx.x * 256 + threadIdx.x) * 4;
  if (e0 < NE) {
    int4 s4 = *(const int4*)&src[e0];
    int4 d4 = *(const int4*)&dst[e0];
    colidx[atomicAdd(&cursor[s4.x], 1)] = d4.x;
    colidx[atomicAdd(&cursor[s4.y], 1)] = d4.y;
    colidx[atomicAdd(&cursor[s4.z], 1)] = d4.z;
    colidx[atomicAdd(&cursor[s4.w], 1)] = d4.w;
  }
}

// ---- attention chunk: each 16-lane group owns one edge per round ----
// Group loads K-row AND V-row (uint4/lane), reduces dot in-group (all lanes
// get the sum), computes e locally, accumulates 8-dim/lane partial output.
// No LDS; colidx broadcast via shfl. 8 wide loads/lane/chunk.
template <bool FULL>
static __device__ __forceinline__ void attn_chunk(
    int base, int cnt, int grp, int gl, int lane, const float* qf,
    const unsigned short* __restrict__ k, const unsigned short* __restrict__ v,
    const int* __restrict__ colidx, float& l, float* ax) {
  const int C = FULL ? 16 : cnt;
  int colreg = 0;
  if (lane < C) colreg = colidx[base + lane];
#pragma unroll
  for (int it = 0; it < 4; it++) {
    const int t = it * 4 + grp;
    const bool act = FULL || t < C;
    const int srcl = act ? t : 0;
    const int c = __shfl(colreg, srcl, 64);
    uint4 kw = *(const uint4*)&k[(size_t)c * ED + gl * 8];
    uint4 vw = *(const uint4*)&v[(size_t)c * ED + gl * 8];
    float2 k0 = bfpair(kw.x), k1 = bfpair(kw.y), k2 = bfpair(kw.z), k3 = bfpair(kw.w);
    float dot = qf[0] * k0.x + qf[1] * k0.y + qf[2] * k1.x + qf[3] * k1.y +
                qf[4] * k2.x + qf[5] * k2.y + qf[6] * k3.x + qf[7] * k3.y;
    dot += __shfl_xor(dot, 1, 64);
    dot += __shfl_xor(dot, 2, 64);
    dot += __shfl_xor(dot, 4, 64);
    dot += __shfl_xor(dot, 8, 64);
    const float e = act ? __expf(dot * 0.08838834764831845f) : 0.f;  // 128^-0.5
    l += e;
    float2 v0 = bfpair(vw.x), v1 = bfpair(vw.y), v2 = bfpair(vw.z), v3 = bfpair(vw.w);
    ax[0] = fmaf(e, v0.x, ax[0]); ax[1] = fmaf(e, v0.y, ax[1]);
    ax[2] = fmaf(e, v1.x, ax[2]); ax[3] = fmaf(e, v1.y, ax[3]);
    ax[4] = fmaf(e, v2.x, ax[4]); ax[5] = fmaf(e, v2.y, ax[5]);
    ax[6] = fmaf(e, v3.x, ax[6]); ax[7] = fmaf(e, v3.y, ax[7]);
  }
}

__global__ __launch_bounds__(256) void k_attn_ln1(
    const unsigned short* __restrict__ q, const unsigned short* __restrict__ k,
    const unsigned short* __restrict__ v, const float* __restrict__ x,
    const int* __restrict__ row_start, const int* __restrict__ colidx,
    const float* __restrict__ g1, const float* __restrict__ be1,
    float* __restrict__ out) {
  const int wv = threadIdx.x >> 6;
  const int lane = threadIdx.x & 63;
  const int grp = lane >> 4, gl = lane & 15;
  const int node = blockIdx.x * 4 + wv;  // NN % 4 == 0

  float qf[8];
  {
    uint4 qw = *(const uint4*)&q[(size_t)node * ED + gl * 8];
    float2 p0 = bfpair(qw.x), p1 = bfpair(qw.y), p2 = bfpair(qw.z), p3 = bfpair(qw.w);
    qf[0] = p0.x; qf[1] = p0.y; qf[2] = p1.x; qf[3] = p1.y;
    qf[4] = p2.x; qf[5] = p2.y; qf[6] = p3.x; qf[7] = p3.y;
  }
  const int r0 = row_start[node], r1 = row_start[node + 1];
  float l = 0.f;
  float ax[8] = {0.f, 0.f, 0.f, 0.f, 0.f, 0.f, 0.f, 0.f};
  int base = r0;
  for (; base + 16 <= r1; base += 16)
    attn_chunk<true>(base, 16, grp, gl, lane, qf, k, v, colidx, l, ax);
  if (base < r1)
    attn_chunk<false>(base, r1 - base, grp, gl, lane, qf, k, v, colidx, l, ax);

  // cross-group reduction: groups hold disjoint edge subsets
#pragma unroll
  for (int j = 0; j < 8; j++) {
    ax[j] += __shfl_xor(ax[j], 16, 64);
    ax[j] += __shfl_xor(ax[j], 32, 64);
  }
  l += __shfl_xor(l, 16, 64);
  l += __shfl_xor(l, 32, 64);

  const float inv = (r1 > r0) ? 1.0f / l : 0.f;
  // this lane outputs dims d0, d0+1 (dims partitioned uniquely over 64 lanes)
  const int d0 = gl * 8 + grp * 2;
  float sx = (grp == 0) ? ax[0] : (grp == 1) ? ax[2] : (grp == 2) ? ax[4] : ax[6];
  float sy = (grp == 0) ? ax[1] : (grp == 1) ? ax[3] : (grp == 2) ? ax[5] : ax[7];
  float2 xv = *(const float2*)&x[(size_t)node * ED + d0];
  float vx = xv.x + sx * inv;
  float vy = xv.y + sy * inv;
  float mean = wave_sum(vx + vy) * (1.f / ED);
  float dx = vx - mean, dy = vy - mean;
  float var = wave_sum(dx * dx + dy * dy) * (1.f / ED);
  float rstd = rsqrtf(var + 1e-5f);
  float2 gg = *(const float2*)&g1[d0];
  float2 bb = *(const float2*)&be1[d0];
  float2 o = make_float2(dx * rstd * gg.x + bb.x, dy * rstd * gg.y + bb.y);
  *(float2*)&out[(size_t)node * ED + d0] = o;
}

// ---- FFN via MFMA: 16 rows/block + residual + LN2, in-place on out ----
__global__ __launch_bounds__(256) void k_ffn_ln2(
    const float* __restrict__ x1, const unsigned short* __restrict__ W1F,
    const float* __restrict__ b1, const unsigned short* __restrict__ W2F,
    const float* __restrict__ b2, const float* __restrict__ g2,
    const float* __restrict__ be2, float* __restrict__ out) {
  __shared__ unsigned short xs[16][136];
  __shared__ unsigned short hs[16][520];  // later aliased ys f32[16][132]
  float* ys = (float*)&hs[0][0];
  const int row0 = blockIdx.x * 16;
  const int tid = threadIdx.x;
  for (int idx = tid; idx < 512; idx += 256) {
    int r = idx >> 5, c4 = (idx & 31) << 2;
    float4 val = *(const float4*)&x1[(size_t)(row0 + r) * ED + c4];
    xs[r][c4] = f2bf(val.x); xs[r][c4 + 1] = f2bf(val.y);
    xs[r][c4 + 2] = f2bf(val.z); xs[r][c4 + 3] = f2bf(val.w);
  }
  __syncthreads();
  const int wv = tid >> 6, lane = tid & 63;
  const int ln = lane & 15, quad = lane >> 4;
  const int koff = quad * 8;
  bf16x8 a1[4];
#pragma unroll
  for (int kb = 0; kb < 4; kb++) a1[kb] = *(const bf16x8*)&xs[ln][kb * 32 + koff];
  for (int g = 0; g < 4; g++) {
    const int t0 = wv * 8 + g * 2;
    bf16x8 b[2][4];
#pragma unroll
    for (int j = 0; j < 2; j++)
#pragma unroll
      for (int kb = 0; kb < 4; kb++)
        b[j][kb] = *(const bf16x8*)&W1F[(size_t)(((t0 + j) * 4 + kb) * 64 + lane) * 8];
    f32x4 acc[2];
#pragma unroll
    for (int j = 0; j < 2; j++) acc[j] = (f32x4){0.f, 0.f, 0.f, 0.f};
#pragma unroll
    for (int kb = 0; kb < 4; kb++)
#pragma unroll
      for (int j = 0; j < 2; j++)
        acc[j] = __builtin_amdgcn_mfma_f32_16x16x32_bf16(a1[kb], b[j][kb], acc[j], 0, 0, 0);
#pragma unroll
    for (int j = 0; j < 2; j++) {
      const int col = (t0 + j) * 16 + ln;
      const float bias = b1[col];
#pragma unroll
      for (int r = 0; r < 4; r++)
        hs[quad * 4 + r][col] = f2bf(fmaxf(acc[j][r] + bias, 0.f));
    }
  }
  __syncthreads();
  f32x4 acc2[2];
  acc2[0] = (f32x4){0.f, 0.f, 0.f, 0.f};
  acc2[1] = (f32x4){0.f, 0.f, 0.f, 0.f};
  const int nt0 = wv * 2;
  for (int kg = 0; kg < 4; kg++) {
    bf16x8 a[4];
#pragma unroll
    for (int kk = 0; kk < 4; kk++)
      a[kk] = *(const bf16x8*)&hs[ln][(kg * 4 + kk) * 32 + koff];
    bf16x8 b[2][4];
#pragma unroll
    for (int nt = 0; nt < 2; nt++)
#pragma unroll
      for (int kk = 0; kk < 4; kk++)
        b[nt][kk] = *(const bf16x8*)&W2F[(size_t)(((nt0 + nt) * 16 + kg * 4 + kk) * 64 + lane) * 8];
#pragma unroll
    for (int kk = 0; kk < 4; kk++)
#pragma unroll
      for (int nt = 0; nt < 2; nt++)
        acc2[nt] = __builtin_amdgcn_mfma_f32_16x16x32_bf16(a[kk], b[nt][kk], acc2[nt], 0, 0, 0);
  }
  __syncthreads();
#pragma unroll
  for (int nt = 0; nt < 2; nt++) {
    const int col = (nt0 + nt) * 16 + ln;
    const float bias = b2[col];
#pragma unroll
    for (int r = 0; r < 4; r++)
      ys[(quad * 4 + r) * 132 + col] = acc2[nt][r] + bias;
  }
  __syncthreads();
  float2 gg = *(const float2*)&g2[2 * lane];
  float2 bbe = *(const float2*)&be2[2 * lane];
#pragma unroll
  for (int rr = 0; rr < 4; rr++) {
    const int r = wv * 4 + rr;
    const int row = row0 + r;
    float2 xr = *(const float2*)&out[(size_t)row * ED + 2 * lane];
    float vx = ys[r * 132 + 2 * lane] + xr.x;
    float vy = ys[r * 132 + 2 * lane + 1] + xr.y;
    float mean = wave_sum(vx + vy) * (1.f / ED);
    float dx = vx - mean, dy = vy - mean;
    float var = wave_sum(dx * dx + dy * dy) * (1.f / ED);
    float rstd = rsqrtf(var + 1e-5f);
    float2 o = make_float2(dx * rstd * gg.x + bbe.x, dy * rstd * gg.y + bbe.y);
    *(float2*)&out[(size_t)row * ED + 2 * lane] = o;
  }
}

extern "C" void kernel_launch(void* const* d_in, const int* in_sizes, int n_in,
                              void* d_out, int out_size, void* d_ws, size_t ws_size,
                              hipStream_t stream) {
  const float* x = (const float*)d_in[0];
  const int* ei = (const int*)d_in[1];
  const float* W_qkv = (const float*)d_in[2];
  const float* b_qkv = (const float*)d_in[3];
  const float* W1 = (const float*)d_in[4];
  const float* b1 = (const float*)d_in[5];
  const float* W2 = (const float*)d_in[6];
  const float* b2 = (const float*)d_in[7];
  const float* g1 = (const float*)d_in[8];
  const float* be1 = (const float*)d_in[9];
  const float* g2 = (const float*)d_in[10];
  const float* be2 = (const float*)d_in[11];
  float* out = (float*)d_out;

  char* ws = (char*)d_ws;
  size_t off = 0;
  auto alloc = [&](size_t bytes) -> char* {
    char* p = ws + off;
    off = (off + bytes + 255) & ~(size_t)255;
    return p;
  };
  unsigned short* q = (unsigned short*)alloc(2 * (size_t)NN * ED);
  unsigned short* k = (unsigned short*)alloc(2 * (size_t)NN * ED);
  unsigned short* v = (unsigned short*)alloc(2 * (size_t)NN * ED);
  unsigned short* WqkvF = (unsigned short*)alloc(2 * 24 * 4 * 64 * 8);
  unsigned short* W1F = (unsigned short*)alloc(2 * 32 * 4 * 64 * 8);
  unsigned short* W2F = (unsigned short*)alloc(2 * 8 * 16 * 64 * 8);
  int* deg = (int*)alloc(sizeof(int) * NN);
  int* cursor = (int*)alloc(sizeof(int) * NN);
  int* row_start = (int*)alloc(sizeof(int) * (NN + 1));
  int* colidx = (int*)alloc(sizeof(int) * NE);
  int* blocksum = (int*)alloc(sizeof(int) * SCAN_BLOCKS);

  k_prep<<<256, 256, 0, stream>>>(W_qkv, W1, W2, WqkvF, W1F, W2F, deg);
  k_qkv_hist<<<QKV_BLOCKS + HIST_BLOCKS, 256, 0, stream>>>(x, WqkvF, b_qkv, q, k, v, ei, deg);
  k_scan1<<<SCAN_BLOCKS, 256, 0, stream>>>(deg, blocksum);
  k_scan3<<<SCAN_BLOCKS, 256, 0, stream>>>(deg, blocksum, row_start, cursor);
  k_scatter<<<HIST_BLOCKS, 256, 0, stream>>>(ei, ei + NE, cursor, colidx);
  k_attn_ln1<<<NN / 4, 256, 0, stream>>>(q, k, v, x, row_start, colidx, g1, be1, out);
  k_ffn_ln2<<<NN / 16, 256, 0, stream>>>(out, W1F, b1, W2F, b2, g2, be2, out);
}